// Round 11
// baseline (293.456 us; speedup 1.0000x reference)
//
#include <hip/hip_runtime.h>
#include <cstdint>

#define K_DIM 4096
#define ROWB 13              // log2(K_DIM*2) byte row stride
#define NU   (K_DIM / 32)    // 128 K-units of 32 cols

typedef __bf16 bf16x8 __attribute__((ext_vector_type(8)));
typedef float f32x4 __attribute__((ext_vector_type(4)));

// round-to-nearest-even float -> bf16 bits
__device__ inline unsigned short f2bf(float f) {
    union { float f; unsigned int u; } v; v.f = f;
    unsigned int u = v.u;
    return (unsigned short)((u + 0x7FFFu + ((u >> 16) & 1u)) >> 16);
}

__device__ __forceinline__ void gload16(const void* g, void* l) {
    __builtin_amdgcn_global_load_lds(
        (const __attribute__((address_space(1))) unsigned int*)g,
        (__attribute__((address_space(3))) unsigned int*)l,
        16, 0, 0);
}

// fused dequant of both operands: out[e] = bf16(q[e] * s[e/16])
__global__ __launch_bounds__(256) void dequant2_kernel(
        const float* __restrict__ qx, const float* __restrict__ sx,
        unsigned short* __restrict__ xd, long t8x,
        const float* __restrict__ qw, const float* __restrict__ sw,
        unsigned short* __restrict__ wd, long t8w) {
    long i = (long)blockIdx.x * blockDim.x + threadIdx.x;
    if (i >= t8x + t8w) return;
    const float* q; const float* s; unsigned short* o;
    if (i < t8x) { q = qx; s = sx; o = xd; }
    else         { q = qw; s = sw; o = wd; i -= t8x; }
    long e = i * 8;
    float sc = s[e >> 4];
    float4 v0 = *(const float4*)(q + e);
    float4 v1 = *(const float4*)(q + e + 4);
    union { unsigned short h[8]; uint4 u; } ov;
    ov.h[0] = f2bf(v0.x * sc); ov.h[1] = f2bf(v0.y * sc);
    ov.h[2] = f2bf(v0.z * sc); ov.h[3] = f2bf(v0.w * sc);
    ov.h[4] = f2bf(v1.x * sc); ov.h[5] = f2bf(v1.y * sc);
    ov.h[6] = f2bf(v1.z * sc); ov.h[7] = f2bf(v1.w * sc);
    *(uint4*)(o + e) = ov.u;
}

// ------------- 256x256 bf16 GEMM — team ping-pong (MFMA || LDS) -------------
// 8 waves (2M x 4N). Team T0 = waves 0-3 (wm=0), T1 = waves 4-7 (wm=1):
// one of each per SIMD under round-robin wave->SIMD mapping. Per K-unit:
//   phase A: stage(u+3) ; T0: 32 MFMA(u)          | T1: 12 ds_read frags(u)
//   barrier
//   phase B:              T0: 12 ds_read frags(u+1)| T1: 32 MFMA(u)
//   vmcnt(4) ; barrier
// -> every phase has one wave/SIMD on the MFMA pipe and one on the LDS
// pipe (wall = max of pipes, not sum). Data path identical to r3 (4 LDS
// slots x 32 KB, chunk-XOR swizzle pre-applied to global source, measured
// 0 bank conflicts). Single frag set per wave: read-then-consume across
// the two phases; register WAR pins the schedule.

__global__ __launch_bounds__(512, 2) void gemm256_kernel(
        const unsigned short* __restrict__ A,   // [M][K] bf16
        const unsigned short* __restrict__ B,   // [N][K] bf16
        const float* __restrict__ sg1, const float* __restrict__ sg2,
        const float* __restrict__ bias,
        float* __restrict__ out, int M, int N) {
    __shared__ __align__(16) char lds[131072];   // 4 slots x 32 KB

    const int tid  = threadIdx.x;
    const int lane = tid & 63;
    const int wid  = tid >> 6;       // 0..7
    const int wm   = wid >> 2;       // 0..1  (= team)
    const int wn   = wid & 3;        // 0..3
    const int l15  = lane & 15;
    const int cb   = (lane >> 4) << 4;                        // frag chunk byte
    const int scb  = ((lane & 3) ^ ((lane >> 3) & 3)) << 4;   // staging src chunk

    // XCD-aware bijective block swizzle (nwg % 8 == 0)
    const int nbn = N >> 8;
    const int nwg = (M >> 8) * nbn;
    const int cpx = nwg >> 3;
    const int bid = blockIdx.x;
    const int swz = (bid & 7) * cpx + (bid >> 3);
    const int tile_m = (swz / nbn) << 8;
    const int tile_n = (swz % nbn) << 8;

    // per-thread global staging cursors (unit-0 addresses); +u*64 per unit
    const int grow = lane >> 2;      // row within 16-row group
    const char* gA0 = (const char*)A +
        ((size_t)(tile_m + 32 * wid + grow) << ROWB) + scb;
    const char* gA1 = gA0 + ((size_t)16 << ROWB);
    const char* gB0 = (const char*)B +
        ((size_t)(tile_n + 32 * wid + grow) << ROWB) + scb;
    const char* gB1 = gB0 + ((size_t)16 << ROWB);
    // LDS staging dest offsets (wave-uniform), within 32KB slot
    const int dA0 = wid * 2048;             // A region [0,16K)
    const int dB0 = 16384 + wid * 2048;     // B region [16K,32K)

    // per-thread LDS fragment read offsets (swizzle XOR invariant across
    // +16-row steps and across units/slots)
    const int arow = wm * 128 + l15;
    const int aoff = arow * 64 + (cb ^ (((arow >> 1) & 3) << 4));  // +mb*1024
    const int brow = wn * 64 + l15;
    const int boff = 16384 + brow * 64 + (cb ^ (((brow >> 1) & 3) << 4));

    f32x4 acc[8][4];
#pragma unroll
    for (int mb = 0; mb < 8; ++mb)
#pragma unroll
        for (int nb = 0; nb < 4; ++nb) acc[mb][nb] = (f32x4){0.f, 0.f, 0.f, 0.f};

    bf16x8 af[8], bf[4];

    // prologue: stage units 0,1,2 into slots 0,1,2
#pragma unroll
    for (int pu = 0; pu < 3; ++pu) {
        char* Sb = lds + (pu << 15);
        const int kb = pu << 6;
        gload16(gA0 + kb, Sb + dA0);
        gload16(gA1 + kb, Sb + dA0 + 1024);
        gload16(gB0 + kb, Sb + dB0);
        gload16(gB1 + kb, Sb + dB0 + 1024);
    }
    // drain units 0,1 (leave unit 2's 4 loads in flight)
    asm volatile("s_waitcnt vmcnt(4)" ::: "memory");
    __builtin_amdgcn_s_barrier();
    // T0 pre-reads frags(0) so it can MFMA(0) in phase A of unit 0
    if (wm == 0) {
#pragma unroll
        for (int nb = 0; nb < 4; ++nb)
            bf[nb] = *(const bf16x8*)(lds + boff + nb * 1024);
#pragma unroll
        for (int mb = 0; mb < 8; ++mb)
            af[mb] = *(const bf16x8*)(lds + aoff + mb * 1024);
    }

#define READ12(S) do {                                                       \
    _Pragma("unroll")                                                        \
    for (int nb = 0; nb < 4; ++nb)                                           \
        bf[nb] = *(const bf16x8*)(lds + (S) + boff + nb * 1024);             \
    _Pragma("unroll")                                                        \
    for (int mb = 0; mb < 8; ++mb)                                           \
        af[mb] = *(const bf16x8*)(lds + (S) + aoff + mb * 1024);             \
} while (0)

#define MFMA32 do {                                                          \
    __builtin_amdgcn_s_setprio(1);                                           \
    _Pragma("unroll")                                                        \
    for (int mb = 0; mb < 8; ++mb)                                           \
        _Pragma("unroll")                                                    \
        for (int nb = 0; nb < 4; ++nb)                                       \
            acc[mb][nb] = __builtin_amdgcn_mfma_f32_16x16x32_bf16(           \
                af[mb], bf[nb], acc[mb][nb], 0, 0, 0);                       \
    __builtin_amdgcn_s_setprio(0);                                           \
} while (0)

#define UNIT_BODY(U, CUR, NXT, STG) do {                                     \
    const int skb = (((U) + 3 < NU) ? (U) + 3 : NU - 1) << 6;                \
    /* phase A: stage(u+3); T0 MFMA(u) | T1 read frags(u) */                 \
    gload16(gA0 + skb, lds + (STG) + dA0);                                   \
    gload16(gA1 + skb, lds + (STG) + dA0 + 1024);                            \
    gload16(gB0 + skb, lds + (STG) + dB0);                                   \
    gload16(gB1 + skb, lds + (STG) + dB0 + 1024);                            \
    if (wm == 0) { MFMA32; } else { READ12(CUR); }                           \
    __builtin_amdgcn_s_barrier();                                            \
    /* phase B: T0 read frags(u+1) | T1 MFMA(u) */                           \
    if (wm == 0) { READ12(NXT); } else { MFMA32; }                           \
    asm volatile("s_waitcnt vmcnt(4)" ::: "memory");                         \
    __builtin_amdgcn_s_barrier();                                            \
} while (0)

    for (int ub = 0; ub < NU; ub += 4) {
        UNIT_BODY(ub + 0, 0,     32768, 98304);
        UNIT_BODY(ub + 1, 32768, 65536, 0);
        UNIT_BODY(ub + 2, 65536, 98304, 32768);
        UNIT_BODY(ub + 3, 98304, 0,     65536);
    }
#undef UNIT_BODY
#undef MFMA32
#undef READ12

    // epilogue: C/D layout col=lane&15, row=(lane>>4)*4+j
    const float gs = sg1[0] * sg2[0];
    const int row0 = tile_m + wm * 128 + ((lane >> 4) << 2);
    const int col0 = tile_n + wn * 64 + l15;
    float bv[4];
#pragma unroll
    for (int nb = 0; nb < 4; ++nb) bv[nb] = bias[col0 + nb * 16];
#pragma unroll
    for (int mb = 0; mb < 8; ++mb)
#pragma unroll
        for (int nb = 0; nb < 4; ++nb) {
            const int col = col0 + nb * 16;
#pragma unroll
            for (int j = 0; j < 4; ++j)
                out[(size_t)(row0 + mb * 16 + j) * N + col] =
                    acc[mb][nb][j] * gs + bv[nb];
        }
}

// ---------------- fallback: fused-dequant 128^2 GEMM (ws too small) ----------------
__global__ __launch_bounds__(256) void gemm_fused_kernel(
        const float* __restrict__ qx, const float* __restrict__ sx,
        const float* __restrict__ qw, const float* __restrict__ sw,
        const float* __restrict__ sg1, const float* __restrict__ sg2,
        const float* __restrict__ bias,
        float* __restrict__ out, int M, int N) {
    __shared__ __align__(16) unsigned short As[128 * 32];
    __shared__ __align__(16) unsigned short Bs[128 * 32];
    const int tid  = threadIdx.x;
    const int lane = tid & 63;
    const int wid  = tid >> 6;
    const int tile_n = blockIdx.x * 128;
    const int tile_m = blockIdx.y * 128;
    const int wm = wid >> 1, wn = wid & 1;
    f32x4 acc[16];
#pragma unroll
    for (int i = 0; i < 16; ++i) acc[i] = (f32x4){0.f, 0.f, 0.f, 0.f};
    const int l15 = lane & 15;
    const int lk  = (lane >> 4) * 8;
    for (int kt = 0; kt < K_DIM / 32; ++kt) {
#pragma unroll
        for (int cc = 0; cc < 2; ++cc) {
            const int c   = tid + cc * 256;
            const int row = c >> 2;
            const int col = (c & 3) * 8;
            const int gk  = kt * 32 + col;
            {
                const float* qp = qx + (long)(tile_m + row) * K_DIM + gk;
                float s = sx[(long)(tile_m + row) * (K_DIM / 16) + (gk >> 4)];
                float4 a0 = *(const float4*)qp;
                float4 a1 = *(const float4*)(qp + 4);
                union { unsigned short h[8]; uint4 u; } o;
                o.h[0] = f2bf(a0.x * s); o.h[1] = f2bf(a0.y * s);
                o.h[2] = f2bf(a0.z * s); o.h[3] = f2bf(a0.w * s);
                o.h[4] = f2bf(a1.x * s); o.h[5] = f2bf(a1.y * s);
                o.h[6] = f2bf(a1.z * s); o.h[7] = f2bf(a1.w * s);
                *(uint4*)&As[row * 32 + col] = o.u;
            }
            {
                const float* qp = qw + (long)(tile_n + row) * K_DIM + gk;
                float s = sw[(long)(tile_n + row) * (K_DIM / 16) + (gk >> 4)];
                float4 a0 = *(const float4*)qp;
                float4 a1 = *(const float4*)(qp + 4);
                union { unsigned short h[8]; uint4 u; } o;
                o.h[0] = f2bf(a0.x * s); o.h[1] = f2bf(a0.y * s);
                o.h[2] = f2bf(a0.z * s); o.h[3] = f2bf(a0.w * s);
                o.h[4] = f2bf(a1.x * s); o.h[5] = f2bf(a1.y * s);
                o.h[6] = f2bf(a1.z * s); o.h[7] = f2bf(a1.w * s);
                *(uint4*)&Bs[row * 32 + col] = o.u;
            }
        }
        __syncthreads();
        const unsigned short* pa = As + (wm * 64 + l15) * 32 + lk;
        const unsigned short* pb = Bs + (wn * 64 + l15) * 32 + lk;
        bf16x8 a[4], b[4];
#pragma unroll
        for (int i = 0; i < 4; ++i) {
            a[i] = *(const bf16x8*)(pa + i * 16 * 32);
            b[i] = *(const bf16x8*)(pb + i * 16 * 32);
        }
#pragma unroll
        for (int mi = 0; mi < 4; ++mi)
#pragma unroll
            for (int ni = 0; ni < 4; ++ni)
                acc[mi * 4 + ni] = __builtin_amdgcn_mfma_f32_16x16x32_bf16(
                    a[mi], b[ni], acc[mi * 4 + ni], 0, 0, 0);
        __syncthreads();
    }
    const float gs = sg1[0] * sg2[0];
    const int row0 = tile_m + wm * 64 + (lane >> 4) * 4;
    const int col0 = tile_n + wn * 64 + l15;
#pragma unroll
    for (int mi = 0; mi < 4; ++mi)
#pragma unroll
        for (int ni = 0; ni < 4; ++ni) {
            const int col = col0 + ni * 16;
            const float bv = bias[col];
#pragma unroll
            for (int j = 0; j < 4; ++j)
                out[(long)(row0 + mi * 16 + j) * N + col] =
                    acc[mi * 4 + ni][j] * gs + bv;
        }
}

extern "C" void kernel_launch(void* const* d_in, const int* in_sizes, int n_in,
                              void* d_out, int out_size, void* d_ws, size_t ws_size,
                              hipStream_t stream) {
    const float* qx   = (const float*)d_in[0];
    const float* sx   = (const float*)d_in[1];
    const float* sc   = (const float*)d_in[2];
    const float* qw   = (const float*)d_in[3];
    const float* sw   = (const float*)d_in[4];
    const float* swg  = (const float*)d_in[5];
    const float* bias = (const float*)d_in[6];
    float* out = (float*)d_out;

    const int M = in_sizes[0] / K_DIM;   // 8192
    const int N = in_sizes[3] / K_DIM;   // 4096

    const size_t needA = (size_t)M * K_DIM * sizeof(unsigned short);
    const size_t needB = (size_t)N * K_DIM * sizeof(unsigned short);

    if (ws_size >= needA + needB) {
        unsigned short* xd = (unsigned short*)d_ws;
        unsigned short* wd = (unsigned short*)((char*)d_ws + needA);
        long t8x = (long)M * K_DIM / 8;
        long t8w = (long)N * K_DIM / 8;
        long tot = t8x + t8w;
        dequant2_kernel<<<(int)((tot + 255) / 256), 256, 0, stream>>>(
            qx, sx, xd, t8x, qw, sw, wd, t8w);
        const int nwg = (M / 256) * (N / 256);
        gemm256_kernel<<<nwg, 512, 0, stream>>>(xd, wd, sc, swg, bias, out, M, N);
    } else {
        dim3 grid(N / 128, M / 128);
        gemm_fused_kernel<<<grid, 256, 0, stream>>>(
            qx, sx, qw, sw, sc, swg, bias, out, M, N);
    }
}

// Round 12
// 272.144 us; speedup vs baseline: 1.0783x; 1.0783x over previous
//
#include <hip/hip_runtime.h>
#include <cstdint>

#define K_DIM 4096
#define ROWB 13              // log2(K_DIM*2) byte row stride
#define NT   (K_DIM / 64)    // 64 K-tiles of 64 cols

typedef __bf16 bf16x8 __attribute__((ext_vector_type(8)));
typedef float f32x4 __attribute__((ext_vector_type(4)));

// round-to-nearest-even float -> bf16 bits
__device__ inline unsigned short f2bf(float f) {
    union { float f; unsigned int u; } v; v.f = f;
    unsigned int u = v.u;
    return (unsigned short)((u + 0x7FFFu + ((u >> 16) & 1u)) >> 16);
}

__device__ __forceinline__ void gload16(const void* g, void* l) {
    __builtin_amdgcn_global_load_lds(
        (const __attribute__((address_space(1))) unsigned int*)g,
        (__attribute__((address_space(3))) unsigned int*)l,
        16, 0, 0);
}

// fused dequant of both operands: out[e] = bf16(q[e] * s[e/16])
__global__ __launch_bounds__(256) void dequant2_kernel(
        const float* __restrict__ qx, const float* __restrict__ sx,
        unsigned short* __restrict__ xd, long t8x,
        const float* __restrict__ qw, const float* __restrict__ sw,
        unsigned short* __restrict__ wd, long t8w) {
    long i = (long)blockIdx.x * blockDim.x + threadIdx.x;
    if (i >= t8x + t8w) return;
    const float* q; const float* s; unsigned short* o;
    if (i < t8x) { q = qx; s = sx; o = xd; }
    else         { q = qw; s = sw; o = wd; i -= t8x; }
    long e = i * 8;
    float sc = s[e >> 4];
    float4 v0 = *(const float4*)(q + e);
    float4 v1 = *(const float4*)(q + e + 4);
    union { unsigned short h[8]; uint4 u; } ov;
    ov.h[0] = f2bf(v0.x * sc); ov.h[1] = f2bf(v0.y * sc);
    ov.h[2] = f2bf(v0.z * sc); ov.h[3] = f2bf(v0.w * sc);
    ov.h[4] = f2bf(v1.x * sc); ov.h[5] = f2bf(v1.y * sc);
    ov.h[6] = f2bf(v1.z * sc); ov.h[7] = f2bf(v1.w * sc);
    *(uint4*)(o + e) = ov.u;
}

// ---- 256x256 bf16 GEMM — snake-quadrant 4-phase (min LDS reads) ----
// 8 waves (2M x 4N), per-wave 128x64 out. BK=64, 2 LDS buffers x 64KB.
// Phases per K-tile (snake order, each reuses one operand set):
//   ph1: read A-lo(8)+B-lo(4) || stage A-lo(next) -> MFMA Q00
//   ph2: read B-hi(4)         || stage B-1(next)  -> MFMA Q01 (A-lo live)
//   ph3: read A-hi(8)         || stage B-2(next)  -> MFMA Q11 (B-hi live)
//   ph4: NO reads             || stage A-hi(next) -> MFMA Q10 (A-hi,B-lo live)
// 24 ds_read_b128/wave/K-tile (minimum for 2x4 wave grid). Counted vmcnt
// ladder (r10-proven): vmcnt(4) at ph2 close, vmcnt(2) at tile boundary.
// Swizzle (128B rows): chunk c of row r at c ^ (r&7), inverse pre-applied
// to per-lane GLOBAL source (LDS dest linear; r9/r10-verified, 0 conflicts).

__global__ __launch_bounds__(512, 2) void gemm256_kernel(
        const unsigned short* __restrict__ A,   // [M][K] bf16
        const unsigned short* __restrict__ B,   // [N][K] bf16
        const float* __restrict__ sg1, const float* __restrict__ sg2,
        const float* __restrict__ bias,
        float* __restrict__ out, int M, int N) {
    __shared__ __align__(16) char lds[131072];   // 2 buffers x 64 KB

    const int tid  = threadIdx.x;
    const int lane = tid & 63;
    const int wid  = tid >> 6;       // 0..7
    const int wm   = wid >> 2;       // 0..1
    const int wn   = wid & 3;        // 0..3
    const int l15  = lane & 15;
    const int cb4  = lane >> 4;      // 0..3: 16B chunk within 32-col ksub
    const int rx   = l15 & 7;        // read-side row XOR
    const int xk0  = (cb4 ^ rx) << 4;
    const int xk1  = ((4 + cb4) ^ rx) << 4;

    // XCD-aware bijective block swizzle (nwg % 8 == 0)
    const int nbn = N >> 8;
    const int nwg = (M >> 8) * nbn;
    const int cpx = nwg >> 3;
    const int bid = blockIdx.x;
    const int swz = (bid & 7) * cpx + (bid >> 3);
    const int tile_m = (swz / nbn) << 8;
    const int tile_n = (swz % nbn) << 8;

    // wave-private staging cursors (tile-0 addresses); +t*128 bytes per K-tile
    const int scb = ((lane & 7) ^ ((lane >> 3) & 7)) << 4;   // pre-swizzled chunk
    const char* gA1 = (const char*)A +
        ((size_t)(tile_m + wm * 128 + wn * 16 + (lane >> 3)) << ROWB) + scb;
    const char* gA2 = gA1 + ((size_t)64 << ROWB);
    const char* gBs = (const char*)B +
        ((size_t)(tile_n + wn * 64 + wm * 32 + (lane >> 3)) << ROWB) + scb;
    // LDS staging dests (wave-uniform bases), within a 64KB buffer
    const int dA1 = (wm * 128 + wn * 16) * 128;          // A at [0,32K)
    const int dA2 = dA1 + 8192;                          // +64 rows
    const int dB  = 32768 + (wn * 64 + wm * 32) * 128;   // B at [32K,64K)

    // fragment read bases (within buffer): +mb*2048 +xk
    const int aB = (wm * 128 + l15) * 128;
    const int bB = 32768 + (wn * 64 + l15) * 128;

    f32x4 acc[8][4];
#pragma unroll
    for (int mb = 0; mb < 8; ++mb)
#pragma unroll
        for (int nb = 0; nb < 4; ++nb) acc[mb][nb] = (f32x4){0.f, 0.f, 0.f, 0.f};

    // prologue: stage tile 0 into buffer 0 (own slices, read order), drain
    gload16(gA1, lds + dA1);
    gload16(gA1 + ((size_t)8 << ROWB), lds + dA1 + 1024);
    gload16(gBs, lds + dB);
    gload16(gBs + ((size_t)8 << ROWB), lds + dB + 1024);
    gload16(gBs + ((size_t)16 << ROWB), lds + dB + 2048);
    gload16(gBs + ((size_t)24 << ROWB), lds + dB + 3072);
    gload16(gA2, lds + dA2);
    gload16(gA2 + ((size_t)8 << ROWB), lds + dA2 + 1024);
    asm volatile("s_waitcnt vmcnt(0)" ::: "memory");
    __builtin_amdgcn_s_barrier();

#define TILE_BODY(T, CB, SB) do {                                            \
    const int ts_ = ((T) + 1 < NT) ? (T) + 1 : NT - 1;                       \
    const size_t tso = (size_t)ts_ * 128;                                    \
    bf16x8 af[8], af2[8], bf[4], bf2[4];                                     \
    /* ---- ph1: read A-lo(8)+B-lo(4) || stage A-lo(next); MFMA Q00 ---- */  \
    _Pragma("unroll")                                                        \
    for (int mb = 0; mb < 4; ++mb) {                                         \
        af[mb * 2 + 0] = *(const bf16x8*)(lds + (CB) + aB + mb * 2048 + xk0);\
        af[mb * 2 + 1] = *(const bf16x8*)(lds + (CB) + aB + mb * 2048 + xk1);\
    }                                                                        \
    _Pragma("unroll")                                                        \
    for (int nb = 0; nb < 2; ++nb) {                                         \
        bf[nb * 2 + 0] = *(const bf16x8*)(lds + (CB) + bB + nb * 2048 + xk0);\
        bf[nb * 2 + 1] = *(const bf16x8*)(lds + (CB) + bB + nb * 2048 + xk1);\
    }                                                                        \
    gload16(gA1 + tso, lds + (SB) + dA1);                                    \
    gload16(gA1 + tso + ((size_t)8 << ROWB), lds + (SB) + dA1 + 1024);       \
    __builtin_amdgcn_s_barrier();                                            \
    asm volatile("s_waitcnt lgkmcnt(0)" ::: "memory");                       \
    __builtin_amdgcn_s_setprio(1);                                           \
    _Pragma("unroll")                                                        \
    for (int mb = 0; mb < 4; ++mb)                                           \
        _Pragma("unroll")                                                    \
        for (int nb = 0; nb < 2; ++nb)                                       \
            _Pragma("unroll")                                                \
            for (int ks = 0; ks < 2; ++ks)                                   \
                acc[mb][nb] = __builtin_amdgcn_mfma_f32_16x16x32_bf16(       \
                    af[mb * 2 + ks], bf[nb * 2 + ks], acc[mb][nb], 0, 0, 0); \
    __builtin_amdgcn_s_setprio(0);                                           \
    __builtin_amdgcn_s_barrier();                                            \
    /* ---- ph2: read B-hi(4) || stage B-1(next); MFMA Q01 (A-lo live) */    \
    _Pragma("unroll")                                                        \
    for (int nb = 0; nb < 2; ++nb) {                                         \
        bf2[nb * 2 + 0] =                                                    \
            *(const bf16x8*)(lds + (CB) + bB + 4096 + nb * 2048 + xk0);      \
        bf2[nb * 2 + 1] =                                                    \
            *(const bf16x8*)(lds + (CB) + bB + 4096 + nb * 2048 + xk1);      \
    }                                                                        \
    gload16(gBs + tso, lds + (SB) + dB);                                     \
    gload16(gBs + tso + ((size_t)8 << ROWB), lds + (SB) + dB + 1024);        \
    __builtin_amdgcn_s_barrier();                                            \
    asm volatile("s_waitcnt lgkmcnt(0)" ::: "memory");                       \
    __builtin_amdgcn_s_setprio(1);                                           \
    _Pragma("unroll")                                                        \
    for (int mb = 0; mb < 4; ++mb)                                           \
        _Pragma("unroll")                                                    \
        for (int nb = 0; nb < 2; ++nb)                                       \
            _Pragma("unroll")                                                \
            for (int ks = 0; ks < 2; ++ks)                                   \
                acc[mb][2 + nb] = __builtin_amdgcn_mfma_f32_16x16x32_bf16(   \
                    af[mb * 2 + ks], bf2[nb * 2 + ks], acc[mb][2 + nb],      \
                    0, 0, 0);                                                \
    __builtin_amdgcn_s_setprio(0);                                           \
    asm volatile("s_waitcnt vmcnt(4)" ::: "memory");                         \
    __builtin_amdgcn_s_barrier();                                            \
    /* ---- ph3: read A-hi(8) || stage B-2(next); MFMA Q11 (B-hi live) */    \
    _Pragma("unroll")                                                        \
    for (int mb = 0; mb < 4; ++mb) {                                         \
        af2[mb * 2 + 0] =                                                    \
            *(const bf16x8*)(lds + (CB) + aB + 8192 + mb * 2048 + xk0);      \
        af2[mb * 2 + 1] =                                                    \
            *(const bf16x8*)(lds + (CB) + aB + 8192 + mb * 2048 + xk1);      \
    }                                                                        \
    gload16(gBs + tso + ((size_t)16 << ROWB), lds + (SB) + dB + 2048);       \
    gload16(gBs + tso + ((size_t)24 << ROWB), lds + (SB) + dB + 3072);       \
    __builtin_amdgcn_s_barrier();                                            \
    asm volatile("s_waitcnt lgkmcnt(0)" ::: "memory");                       \
    __builtin_amdgcn_s_setprio(1);                                           \
    _Pragma("unroll")                                                        \
    for (int mb = 0; mb < 4; ++mb)                                           \
        _Pragma("unroll")                                                    \
        for (int nb = 0; nb < 2; ++nb)                                       \
            _Pragma("unroll")                                                \
            for (int ks = 0; ks < 2; ++ks)                                   \
                acc[4 + mb][2 + nb] = __builtin_amdgcn_mfma_f32_16x16x32_bf16(\
                    af2[mb * 2 + ks], bf2[nb * 2 + ks], acc[4 + mb][2 + nb], \
                    0, 0, 0);                                                \
    __builtin_amdgcn_s_setprio(0);                                           \
    __builtin_amdgcn_s_barrier();                                            \
    /* ---- ph4: NO reads || stage A-hi(next); MFMA Q10 (A-hi,B-lo live) */  \
    gload16(gA2 + tso, lds + (SB) + dA2);                                    \
    gload16(gA2 + tso + ((size_t)8 << ROWB), lds + (SB) + dA2 + 1024);       \
    __builtin_amdgcn_s_setprio(1);                                           \
    _Pragma("unroll")                                                        \
    for (int mb = 0; mb < 4; ++mb)                                           \
        _Pragma("unroll")                                                    \
        for (int nb = 0; nb < 2; ++nb)                                       \
            _Pragma("unroll")                                                \
            for (int ks = 0; ks < 2; ++ks)                                   \
                acc[4 + mb][nb] = __builtin_amdgcn_mfma_f32_16x16x32_bf16(   \
                    af2[mb * 2 + ks], bf[nb * 2 + ks], acc[4 + mb][nb],      \
                    0, 0, 0);                                                \
    __builtin_amdgcn_s_setprio(0);                                           \
    asm volatile("s_waitcnt vmcnt(2)" ::: "memory");                         \
    __builtin_amdgcn_s_barrier();                                            \
} while (0)

    for (int t = 0; t < NT; t += 2) {
        TILE_BODY(t,     0,     65536);
        TILE_BODY(t + 1, 65536, 0);
    }
#undef TILE_BODY

    // epilogue: C/D layout col=lane&15, row=(lane>>4)*4+j
    const float gs = sg1[0] * sg2[0];
    const int row0 = tile_m + wm * 128 + (cb4 << 2);
    const int col0 = tile_n + wn * 64 + l15;
    float bv[4];
#pragma unroll
    for (int nb = 0; nb < 4; ++nb) bv[nb] = bias[col0 + nb * 16];
#pragma unroll
    for (int mb = 0; mb < 8; ++mb)
#pragma unroll
        for (int nb = 0; nb < 4; ++nb) {
            const int col = col0 + nb * 16;
#pragma unroll
            for (int j = 0; j < 4; ++j)
                out[(size_t)(row0 + mb * 16 + j) * N + col] =
                    acc[mb][nb][j] * gs + bv[nb];
        }
}

// ---------------- fallback: fused-dequant 128^2 GEMM (ws too small) ----------------
__global__ __launch_bounds__(256) void gemm_fused_kernel(
        const float* __restrict__ qx, const float* __restrict__ sx,
        const float* __restrict__ qw, const float* __restrict__ sw,
        const float* __restrict__ sg1, const float* __restrict__ sg2,
        const float* __restrict__ bias,
        float* __restrict__ out, int M, int N) {
    __shared__ __align__(16) unsigned short As[128 * 32];
    __shared__ __align__(16) unsigned short Bs[128 * 32];
    const int tid  = threadIdx.x;
    const int lane = tid & 63;
    const int wid  = tid >> 6;
    const int tile_n = blockIdx.x * 128;
    const int tile_m = blockIdx.y * 128;
    const int wm = wid >> 1, wn = wid & 1;
    f32x4 acc[16];
#pragma unroll
    for (int i = 0; i < 16; ++i) acc[i] = (f32x4){0.f, 0.f, 0.f, 0.f};
    const int l15 = lane & 15;
    const int lk  = (lane >> 4) * 8;
    for (int kt = 0; kt < K_DIM / 32; ++kt) {
#pragma unroll
        for (int cc = 0; cc < 2; ++cc) {
            const int c   = tid + cc * 256;
            const int row = c >> 2;
            const int col = (c & 3) * 8;
            const int gk  = kt * 32 + col;
            {
                const float* qp = qx + (long)(tile_m + row) * K_DIM + gk;
                float s = sx[(long)(tile_m + row) * (K_DIM / 16) + (gk >> 4)];
                float4 a0 = *(const float4*)qp;
                float4 a1 = *(const float4*)(qp + 4);
                union { unsigned short h[8]; uint4 u; } o;
                o.h[0] = f2bf(a0.x * s); o.h[1] = f2bf(a0.y * s);
                o.h[2] = f2bf(a0.z * s); o.h[3] = f2bf(a0.w * s);
                o.h[4] = f2bf(a1.x * s); o.h[5] = f2bf(a1.y * s);
                o.h[6] = f2bf(a1.z * s); o.h[7] = f2bf(a1.w * s);
                *(uint4*)&As[row * 32 + col] = o.u;
            }
            {
                const float* qp = qw + (long)(tile_n + row) * K_DIM + gk;
                float s = sw[(long)(tile_n + row) * (K_DIM / 16) + (gk >> 4)];
                float4 a0 = *(const float4*)qp;
                float4 a1 = *(const float4*)(qp + 4);
                union { unsigned short h[8]; uint4 u; } o;
                o.h[0] = f2bf(a0.x * s); o.h[1] = f2bf(a0.y * s);
                o.h[2] = f2bf(a0.z * s); o.h[3] = f2bf(a0.w * s);
                o.h[4] = f2bf(a1.x * s); o.h[5] = f2bf(a1.y * s);
                o.h[6] = f2bf(a1.z * s); o.h[7] = f2bf(a1.w * s);
                *(uint4*)&Bs[row * 32 + col] = o.u;
            }
        }
        __syncthreads();
        const unsigned short* pa = As + (wm * 64 + l15) * 32 + lk;
        const unsigned short* pb = Bs + (wn * 64 + l15) * 32 + lk;
        bf16x8 a[4], b[4];
#pragma unroll
        for (int i = 0; i < 4; ++i) {
            a[i] = *(const bf16x8*)(pa + i * 16 * 32);
            b[i] = *(const bf16x8*)(pb + i * 16 * 32);
        }
#pragma unroll
        for (int mi = 0; mi < 4; ++mi)
#pragma unroll
            for (int ni = 0; ni < 4; ++ni)
                acc[mi * 4 + ni] = __builtin_amdgcn_mfma_f32_16x16x32_bf16(
                    a[mi], b[ni], acc[mi * 4 + ni], 0, 0, 0);
        __syncthreads();
    }
    const float gs = sg1[0] * sg2[0];
    const int row0 = tile_m + wm * 64 + (lane >> 4) * 4;
    const int col0 = tile_n + wn * 64 + l15;
#pragma unroll
    for (int mi = 0; mi < 4; ++mi)
#pragma unroll
        for (int ni = 0; ni < 4; ++ni) {
            const int col = col0 + ni * 16;
            const float bv = bias[col];
#pragma unroll
            for (int j = 0; j < 4; ++j)
                out[(long)(row0 + mi * 16 + j) * N + col] =
                    acc[mi * 4 + ni][j] * gs + bv;
        }
}

extern "C" void kernel_launch(void* const* d_in, const int* in_sizes, int n_in,
                              void* d_out, int out_size, void* d_ws, size_t ws_size,
                              hipStream_t stream) {
    const float* qx   = (const float*)d_in[0];
    const float* sx   = (const float*)d_in[1];
    const float* sc   = (const float*)d_in[2];
    const float* qw   = (const float*)d_in[3];
    const float* sw   = (const float*)d_in[4];
    const float* swg  = (const float*)d_in[5];
    const float* bias = (const float*)d_in[6];
    float* out = (float*)d_out;

    const int M = in_sizes[0] / K_DIM;   // 8192
    const int N = in_sizes[3] / K_DIM;   // 4096

    const size_t needA = (size_t)M * K_DIM * sizeof(unsigned short);
    const size_t needB = (size_t)N * K_DIM * sizeof(unsigned short);

    if (ws_size >= needA + needB) {
        unsigned short* xd = (unsigned short*)d_ws;
        unsigned short* wd = (unsigned short*)((char*)d_ws + needA);
        long t8x = (long)M * K_DIM / 8;
        long t8w = (long)N * K_DIM / 8;
        long tot = t8x + t8w;
        dequant2_kernel<<<(int)((tot + 255) / 256), 256, 0, stream>>>(
            qx, sx, xd, t8x, qw, sw, wd, t8w);
        const int nwg = (M / 256) * (N / 256);
        gemm256_kernel<<<nwg, 512, 0, stream>>>(xd, wd, sc, swg, bias, out, M, N);
    } else {
        dim3 grid(N / 128, M / 128);
        gemm_fused_kernel<<<grid, 256, 0, stream>>>(
            qx, sx, qw, sw, sc, swg, bias, out, M, N);
    }
}